// Round 1
// baseline (138.186 us; speedup 1.0000x reference)
//
#include <hip/hip_runtime.h>

#define NTOK   65536
#define DHALF  512     // D_CONTENT == D_POS
#define DEMB   1024
#define EPS    1e-3f

__device__ __forceinline__ float4 f4add(float4 a, float4 b) {
    return make_float4(a.x + b.x, a.y + b.y, a.z + b.z, a.w + b.w);
}
__device__ __forceinline__ float f4sum(float4 a) { return a.x + a.y + a.z + a.w; }

__global__ __launch_bounds__(256) void mle_kernel(
    const int* __restrict__ x0, const int* __restrict__ x1,
    const int* __restrict__ pos_ids,
    const float* __restrict__ emb0, const float* __restrict__ emb1,
    const float* __restrict__ post,
    const float* __restrict__ a2, const float* __restrict__ b2,
    float* __restrict__ ann, float* __restrict__ timing, int T)
{
    const int gtid = blockIdx.x * blockDim.x + threadIdx.x;
    const int tok  = gtid >> 6;          // one wave (64 lanes) per token
    const int lane = threadIdx.x & 63;
    if (tok >= T) return;

    const int i0 = x0[tok];
    const int i1 = x1[tok];
    const int ip = pos_ids[tok];

    const float4* r0 = (const float4*)(emb0 + (size_t)i0 * DHALF);
    const float4* r1 = (const float4*)(emb1 + (size_t)i1 * DHALF);
    const float4* rp = (const float4*)(post + (size_t)ip * DHALF);

    // Each half-row is 128 float4s; lane covers vec {lane, lane+64} of each half.
    float4 cl = f4add(r0[lane],      r1[lane]);       // z vecs [lane]      (content lo)
    float4 ch = f4add(r0[lane + 64], r1[lane + 64]);  // z vecs [64+lane]   (content hi)
    float4 tl = rp[lane];                             // z vecs [128+lane]  (timing lo)
    float4 th = rp[lane + 64];                        // z vecs [192+lane]  (timing hi)

    // --- mean over 1024 elems (exact two-pass, all values live in regs) ---
    float s = f4sum(cl) + f4sum(ch) + f4sum(tl) + f4sum(th);
    #pragma unroll
    for (int off = 32; off > 0; off >>= 1) s += __shfl_xor(s, off);
    const float mu = s * (1.0f / (float)DEMB);

    float4 zcl = make_float4(cl.x - mu, cl.y - mu, cl.z - mu, cl.w - mu);
    float4 zch = make_float4(ch.x - mu, ch.y - mu, ch.z - mu, ch.w - mu);
    float4 ztl = make_float4(tl.x - mu, tl.y - mu, tl.z - mu, tl.w - mu);
    float4 zth = make_float4(th.x - mu, th.y - mu, th.z - mu, th.w - mu);

    float q = zcl.x*zcl.x + zcl.y*zcl.y + zcl.z*zcl.z + zcl.w*zcl.w
            + zch.x*zch.x + zch.y*zch.y + zch.z*zch.z + zch.w*zch.w
            + ztl.x*ztl.x + ztl.y*ztl.y + ztl.z*ztl.z + ztl.w*ztl.w
            + zth.x*zth.x + zth.y*zth.y + zth.z*zth.z + zth.w*zth.w;
    #pragma unroll
    for (int off = 32; off > 0; off >>= 1) q += __shfl_xor(q, off);

    const float sigma = sqrtf(q * (1.0f / (float)(DEMB - 1)));  // unbiased (ddof=1)
    const float inv   = 1.0f / (sigma + EPS);

    // --- scale/shift (a2/b2 are 4KB each -> cache-resident) ---
    const float4* A = (const float4*)a2;
    const float4* Bv = (const float4*)b2;
    float4 acl = A[lane],        bcl = Bv[lane];
    float4 ach = A[lane + 64],   bch = Bv[lane + 64];
    float4 atl = A[lane + 128],  btl = Bv[lane + 128];
    float4 ath = A[lane + 192],  bth = Bv[lane + 192];

    float4 ocl = make_float4(zcl.x*inv*acl.x + bcl.x, zcl.y*inv*acl.y + bcl.y,
                             zcl.z*inv*acl.z + bcl.z, zcl.w*inv*acl.w + bcl.w);
    float4 och = make_float4(zch.x*inv*ach.x + bch.x, zch.y*inv*ach.y + bch.y,
                             zch.z*inv*ach.z + bch.z, zch.w*inv*ach.w + bch.w);
    float4 otl = make_float4(ztl.x*inv*atl.x + btl.x, ztl.y*inv*atl.y + btl.y,
                             ztl.z*inv*atl.z + btl.z, ztl.w*inv*atl.w + btl.w);
    float4 oth = make_float4(zth.x*inv*ath.x + bth.x, zth.y*inv*ath.y + bth.y,
                             zth.z*inv*ath.z + bth.z, zth.w*inv*ath.w + bth.w);

    // --- stores (coalesced float4) ---
    float4* annv = (float4*)(ann + (size_t)tok * DEMB);
    annv[lane]       = ocl;
    annv[lane + 64]  = och;
    annv[lane + 128] = otl;
    annv[lane + 192] = oth;

    float4* timv = (float4*)(timing + (size_t)tok * DHALF);
    timv[lane]      = tl;
    timv[lane + 64] = th;
}

extern "C" void kernel_launch(void* const* d_in, const int* in_sizes, int n_in,
                              void* d_out, int out_size, void* d_ws, size_t ws_size,
                              hipStream_t stream) {
    const int*   x0     = (const int*)d_in[0];
    const int*   x1     = (const int*)d_in[1];
    const int*   pos    = (const int*)d_in[2];
    const float* emb0   = (const float*)d_in[3];
    const float* emb1   = (const float*)d_in[4];
    const float* ptab   = (const float*)d_in[5];
    const float* a2     = (const float*)d_in[6];
    const float* b2     = (const float*)d_in[7];

    const int T = in_sizes[0];                       // 65536 tokens
    float* out    = (float*)d_out;
    float* ann    = out;                             // [T, 1024]
    float* timing = out + (size_t)T * DEMB;          // [T, 512]

    const int threads = 256;                         // 4 waves = 4 tokens / block
    const int blocks  = (T * 64 + threads - 1) / threads;
    mle_kernel<<<blocks, threads, 0, stream>>>(x0, x1, pos, emb0, emb1, ptab,
                                               a2, b2, ann, timing, T);
}

// Round 2
// 103.060 us; speedup vs baseline: 1.3408x; 1.3408x over previous
//
#include <hip/hip_runtime.h>

#define DHALF  512     // D_CONTENT == D_POS
#define DEMB   1024
#define EPS    1e-3f

typedef float __attribute__((ext_vector_type(4))) f32x4;

__device__ __forceinline__ float4 f4add(float4 a, float4 b) {
    return make_float4(a.x + b.x, a.y + b.y, a.z + b.z, a.w + b.w);
}
__device__ __forceinline__ float f4sum(float4 a) { return a.x + a.y + a.z + a.w; }

__device__ __forceinline__ void nt_store4(float4 v, float4* p) {
    f32x4 t; t.x = v.x; t.y = v.y; t.z = v.z; t.w = v.w;
    __builtin_nontemporal_store(t, (f32x4*)p);
}

__global__ __launch_bounds__(256) void mle_kernel(
    const int* __restrict__ x0, const int* __restrict__ x1,
    const int* __restrict__ pos_ids,
    const float* __restrict__ emb0, const float* __restrict__ emb1,
    const float* __restrict__ post,
    const float* __restrict__ a2, const float* __restrict__ b2,
    float* __restrict__ ann, float* __restrict__ timing, int T)
{
    const int gtid = blockIdx.x * blockDim.x + threadIdx.x;
    const int tok  = gtid >> 6;          // one wave (64 lanes) per token
    const int lane = threadIdx.x & 63;
    if (tok >= T) return;

    const int i0 = x0[tok];
    const int i1 = x1[tok];
    const int ip = pos_ids[tok];

    const float4* r0 = (const float4*)(emb0 + (size_t)i0 * DHALF);
    const float4* r1 = (const float4*)(emb1 + (size_t)i1 * DHALF);
    const float4* rp = (const float4*)(post + (size_t)ip * DHALF);

    // Each half-row is 128 float4s; lane covers vec {lane, lane+64} of each half.
    float4 cl = f4add(r0[lane],      r1[lane]);       // z vecs [lane]      (content lo)
    float4 ch = f4add(r0[lane + 64], r1[lane + 64]);  // z vecs [64+lane]   (content hi)
    float4 tl = rp[lane];                             // z vecs [128+lane]  (timing lo)
    float4 th = rp[lane + 64];                        // z vecs [192+lane]  (timing hi)

    // timing output is ready now — issue streaming stores before the reductions
    float4* timv = (float4*)(timing + (size_t)tok * DHALF);
    nt_store4(tl, &timv[lane]);
    nt_store4(th, &timv[lane + 64]);

    // a2/b2 loads are independent — issue before the reduction chains
    const float4* A  = (const float4*)a2;
    const float4* Bv = (const float4*)b2;
    float4 acl = A[lane],        bcl = Bv[lane];
    float4 ach = A[lane + 64],   bch = Bv[lane + 64];
    float4 atl = A[lane + 128],  btl = Bv[lane + 128];
    float4 ath = A[lane + 192],  bth = Bv[lane + 192];

    // --- mean over 1024 elems (exact two-pass, all values live in regs) ---
    float s = f4sum(cl) + f4sum(ch) + f4sum(tl) + f4sum(th);
    #pragma unroll
    for (int off = 32; off > 0; off >>= 1) s += __shfl_xor(s, off);
    const float mu = s * (1.0f / (float)DEMB);

    float4 zcl = make_float4(cl.x - mu, cl.y - mu, cl.z - mu, cl.w - mu);
    float4 zch = make_float4(ch.x - mu, ch.y - mu, ch.z - mu, ch.w - mu);
    float4 ztl = make_float4(tl.x - mu, tl.y - mu, tl.z - mu, tl.w - mu);
    float4 zth = make_float4(th.x - mu, th.y - mu, th.z - mu, th.w - mu);

    float q = zcl.x*zcl.x + zcl.y*zcl.y + zcl.z*zcl.z + zcl.w*zcl.w
            + zch.x*zch.x + zch.y*zch.y + zch.z*zch.z + zch.w*zch.w
            + ztl.x*ztl.x + ztl.y*ztl.y + ztl.z*ztl.z + ztl.w*ztl.w
            + zth.x*zth.x + zth.y*zth.y + zth.z*zth.z + zth.w*zth.w;
    #pragma unroll
    for (int off = 32; off > 0; off >>= 1) q += __shfl_xor(q, off);

    const float sigma = sqrtf(q * (1.0f / (float)(DEMB - 1)));  // unbiased (ddof=1)
    const float inv   = 1.0f / (sigma + EPS);

    float4 ocl = make_float4(zcl.x*inv*acl.x + bcl.x, zcl.y*inv*acl.y + bcl.y,
                             zcl.z*inv*acl.z + bcl.z, zcl.w*inv*acl.w + bcl.w);
    float4 och = make_float4(zch.x*inv*ach.x + bch.x, zch.y*inv*ach.y + bch.y,
                             zch.z*inv*ach.z + bch.z, zch.w*inv*ach.w + bch.w);
    float4 otl = make_float4(ztl.x*inv*atl.x + btl.x, ztl.y*inv*atl.y + btl.y,
                             ztl.z*inv*atl.z + btl.z, ztl.w*inv*atl.w + btl.w);
    float4 oth = make_float4(zth.x*inv*ath.x + bth.x, zth.y*inv*ath.y + bth.y,
                             zth.z*inv*ath.z + bth.z, zth.w*inv*ath.w + bth.w);

    // --- annotation stores (coalesced float4, streaming) ---
    float4* annv = (float4*)(ann + (size_t)tok * DEMB);
    nt_store4(ocl, &annv[lane]);
    nt_store4(och, &annv[lane + 64]);
    nt_store4(otl, &annv[lane + 128]);
    nt_store4(oth, &annv[lane + 192]);
}

extern "C" void kernel_launch(void* const* d_in, const int* in_sizes, int n_in,
                              void* d_out, int out_size, void* d_ws, size_t ws_size,
                              hipStream_t stream) {
    const int*   x0     = (const int*)d_in[0];
    const int*   x1     = (const int*)d_in[1];
    const int*   pos    = (const int*)d_in[2];
    const float* emb0   = (const float*)d_in[3];
    const float* emb1   = (const float*)d_in[4];
    const float* ptab   = (const float*)d_in[5];
    const float* a2     = (const float*)d_in[6];
    const float* b2     = (const float*)d_in[7];

    const int T = in_sizes[0];                       // 65536 tokens
    float* out    = (float*)d_out;
    float* ann    = out;                             // [T, 1024]
    float* timing = out + (size_t)T * DEMB;          // [T, 512]

    const int threads = 256;                         // 4 waves = 4 tokens / block
    const int blocks  = (T * 64 + threads - 1) / threads;
    mle_kernel<<<blocks, threads, 0, stream>>>(x0, x1, pos, emb0, emb1, ptab,
                                               a2, b2, ann, timing, T);
}